// Round 12
// baseline (4063.372 us; speedup 1.0000x reference)
//
#include <hip/hip_runtime.h>

typedef __attribute__((ext_vector_type(8))) short short8;
typedef __attribute__((ext_vector_type(16))) float f32x16;
typedef __attribute__((ext_vector_type(2))) unsigned int u32x2;
typedef unsigned short u16;
typedef unsigned int u32;

// ---------------- workspace layout (bytes) ----------------
// xb:  [512 t][2 w][64 c][32 b][8 u] bf16                    = 33,554,432
// h0h: [513 t][2 w][128 c][32 b][8 u] bf16 (slot t+1 = h[t]) = 67,239,936
// h1h: same                                                  = 67,239,936
// flags: [2 layer][2 w][128 chunk] monotonic, 32B stride     = 16,384
#define XB_OFF 0ul
#define H0_OFF 33554432ul
#define H1_OFF 100794368ul
#define FL_OFF 168034304ul
#define FLAGS_LEN 16384ul

#define LDS_TOTAL 131584   // 32 cols * (2*2048 + 16) pad; L0 uses 32*(3072+16)

__device__ __forceinline__ u16 f2bf(float f) {
  u32 u = __float_as_uint(f);
  return (u16)((u + 0x7fffu + ((u >> 16) & 1u)) >> 16);   // RNE
}
__device__ __forceinline__ float bf2f(u16 s) { return __uint_as_float(((u32)s) << 16); }

// x[b][t][i] fp32 -> xb[t][w][c][b'][u] bf16 (chunked layout matching h)
__global__ __launch_bounds__(256) void prep_x(const float* __restrict__ x,
                                              u16* __restrict__ xb) {
  u32 stride = gridDim.x * blockDim.x;
  for (u32 e = blockIdx.x * blockDim.x + threadIdx.x; e < 16777216u; e += stride) {
    u32 t = e >> 15;
    u32 r = e & 32767u;
    u32 w = r >> 14;
    u32 r2 = r & 16383u;
    u32 c = r2 >> 8;
    u32 r3 = r2 & 255u;
    u32 b = r3 >> 3, u = r3 & 7u;
    u32 gb = w * 32u + b;
    xb[e] = f2bf(x[(size_t)gb * 262144 + (size_t)t * 512 + c * 8 + u]);
  }
}

// Persistent kernel: 256 blocks (1/CU) x 128 threads (2 waves).
// Blocks 0..127: layer0 (K=1536=[x|h0prev]); 128..255: layer1 (K=2048=[h0|h1prev]).
// Wave w = batch class (32 batches). mfma_32x32x16(A=W cols, B=h): C row = gate-col,
// col = batch -> each lane holds i,f,g,o of 4 units for ONE batch: cell update is
// fully lane-local (no shfl, no LDS reduce, no barriers in the main loop).
// Software-pipelined: poll f1 -> issue H1 -> poll f0 (overlaps flight) -> issue H0
// -> MFMA sweeps with in-flight refills. 4 K-parity accumulators.
__global__ __launch_bounds__(128, 1) void lstm_persist(
    const u16* __restrict__ xb,
    const float* __restrict__ wih0, const float* __restrict__ whh0,
    const float* __restrict__ bih0, const float* __restrict__ bhh0,
    const float* __restrict__ wih1, const float* __restrict__ whh1,
    const float* __restrict__ bih1, const float* __restrict__ bhh1,
    u16* __restrict__ h0h, u16* __restrict__ h1h,
    u32* __restrict__ flags,
    const float* __restrict__ fc_w, const float* __restrict__ fc_b,
    float* __restrict__ out) {
  extern __shared__ char smem[];
  const int cu = blockIdx.x;
  const int layer = cu >> 7;
  const int lcu = cu & 127;
  const int U0 = lcu * 8;
  const int K2P = layer ? (4096 + 16) : (3072 + 16);   // padded col stride (bytes)
  const int tid = threadIdx.x;

  // ---- startup: pack 32 weight cols (col-major k, +16B pad, no XOR) ----
  for (int n = 0; n < 32; ++n) {
    const int grow = (n >> 3) * 1024 + U0 + (n & 7);
    u16* colbase = (u16*)(smem + n * K2P);
    if (!layer) {
      const float* rih = wih0 + (size_t)grow * 512;
      const float* rhh = whh0 + (size_t)grow * 1024;
      for (int k = tid; k < 1536; k += 128)
        colbase[k] = f2bf(k < 512 ? rih[k] : rhh[k - 512]);
    } else {
      const float* rih = wih1 + (size_t)grow * 1024;
      const float* rhh = whh1 + (size_t)grow * 1024;
      for (int k = tid; k < 2048; k += 128)
        colbase[k] = f2bf(k < 1024 ? rih[k] : rhh[k - 1024]);
    }
  }
  __syncthreads();   // last barrier before the main loop

  const int w = tid >> 6;            // batch class (32 batches)
  const int lane = tid & 63;
  const int b = lane & 31;           // batch within class; also W row (gate-col)
  const int hi = lane >> 5;          // k-half / unit-half selector
  const char* wbase = smem + (size_t)(lane & 31) * K2P + hi * 16;

  // per-lane bias regs: units u = 4*hi + r
  float bi[4], bf_[4], bg[4], bo[4];
  {
    const float* s1 = layer ? bih1 : bih0;
    const float* s2 = layer ? bhh1 : bhh0;
    const int ug = U0 + 4 * hi;
    #pragma unroll
    for (int r = 0; r < 4; ++r) {
      bi[r]  = s1[ug + r]        + s2[ug + r];
      bf_[r] = s1[1024 + ug + r] + s2[1024 + ug + r];
      bg[r]  = s1[2048 + ug + r] + s2[2048 + ug + r];
      bo[r]  = s1[3072 + ug + r] + s2[3072 + ug + r];
    }
  }
  float cs[4] = {0.f, 0.f, 0.f, 0.f};

  const u32* f0w = flags + (size_t)(0 * 2 + w) * 128 * 8;
  const u32* f1w = flags + (size_t)(1 * 2 + w) * 128 * 8;
  u32* myflag = flags + ((size_t)(layer * 2 + w) * 128 + (size_t)lcu) * 8;

  // wave poll: all 128 chunk flags of (srclayer, w) >= target
  auto poll = [&](const u32* base, u32 target) {
    const u32* p1 = base + (u32)lane * 8u;
    const u32* p2 = base + (u32)(lane + 64) * 8u;
    for (;;) {
      u32 v1, v2;
      asm volatile("global_load_dword %0, %2, off sc0 sc1\n\t"
                   "global_load_dword %1, %3, off sc0 sc1\n\t"
                   "s_waitcnt vmcnt(0)"
                   : "=v"(v1), "=v"(v2) : "v"(p1), "v"(p2) : "memory");
      if (__all((int)((v1 >= target) & (v2 >= target)))) break;
      __builtin_amdgcn_s_sleep(1);
    }
  };

  f32x16 acc[4];

  auto publish = [&](int t, u16* hist) {
    f32x16 s;
    #pragma unroll
    for (int r = 0; r < 16; ++r) s[r] = acc[0][r] + acc[1][r] + acc[2][r] + acc[3][r];
    float hv[4];
    #pragma unroll
    for (int r = 0; r < 4; ++r) {
      float gi = s[r]      + bi[r];
      float gf = s[4 + r]  + bf_[r];
      float gg = s[8 + r]  + bg[r];
      float go = s[12 + r] + bo[r];
      float ii = 1.0f / (1.0f + __expf(-gi));
      float ff = 1.0f / (1.0f + __expf(-gf));
      float gt = 1.0f - 2.0f / (__expf(2.0f * gg) + 1.0f);
      float oo = 1.0f / (1.0f + __expf(-go));
      cs[r] = ff * cs[r] + ii * gt;
      hv[r] = oo * (1.0f - 2.0f / (__expf(2.0f * cs[r]) + 1.0f));
    }
    u32x2 pk;
    pk.x = (u32)f2bf(hv[0]) | ((u32)f2bf(hv[1]) << 16);
    pk.y = (u32)f2bf(hv[2]) | ((u32)f2bf(hv[3]) << 16);
    u16* dst = hist + (size_t)(t + 1) * 65536 + (size_t)w * 32768
               + (size_t)lcu * 256 + (size_t)b * 8 + 4 * hi;
    asm volatile("global_store_dwordx2 %0, %1, off sc0 sc1" :: "v"(dst), "v"(pk));
    asm volatile("s_waitcnt vmcnt(0)" ::: "memory");   // wave's data stores ack'd
    if (lane == 0)
      asm volatile("global_store_dword %0, %1, off sc0 sc1"
                   :: "v"(myflag), "v"((u32)(t + 1)));
  };

  // one MFMA: A = W frag (16B from LDS at tile*32), B = h/x frag from register
  #define MFMA_T(buf, tile) do {                                            \
    short8 _a = *(const short8*)(wbase + (tile) * 32);                      \
    acc[(tile) & 3] = __builtin_amdgcn_mfma_f32_32x32x16_bf16(              \
        _a, (buf), acc[(tile) & 3], 0, 0, 0);                               \
  } while (0)

  if (!layer) {
    // ================= layer 0: tiles 0..31 = x, 32..95 = h0prev ============
    for (int t = 0; t < 512; ++t) {
      #pragma unroll
      for (int a = 0; a < 4; ++a)
        #pragma unroll
        for (int r = 0; r < 16; ++r) acc[a][r] = 0.f;
      short8 U[32], V[32];
      const u16* xp = xb + (size_t)t * 32768 + (size_t)w * 16384
                      + (size_t)hi * 256 + (size_t)b * 8;
      #pragma unroll
      for (int j = 0; j < 32; ++j) U[j] = *(const short8*)(xp + j * 512);
      const u16* hp = h0h + (size_t)t * 65536 + (size_t)w * 32768
                      + (size_t)hi * 256 + (size_t)b * 8;
      if (t > 0) {
        poll(f0w, (u32)t);
        #pragma unroll
        for (int j = 0; j < 32; ++j) V[j] = *(const short8*)(hp + j * 512);
      }
      #pragma unroll
      for (int j = 0; j < 32; ++j) MFMA_T(U[j], j);
      if (t > 0) {
        #pragma unroll
        for (int j = 0; j < 32; ++j) U[j] = *(const short8*)(hp + 16384 + j * 512);
        #pragma unroll
        for (int j = 0; j < 32; ++j) MFMA_T(V[j], 32 + j);
        #pragma unroll
        for (int j = 0; j < 32; ++j) MFMA_T(U[j], 64 + j);
      }
      publish(t, h0h);
    }
  } else {
    // ============== layer 1: tiles 0..63 = h0cur, 64..127 = h1prev ==========
    for (int t = 0; t < 512; ++t) {
      #pragma unroll
      for (int a = 0; a < 4; ++a)
        #pragma unroll
        for (int r = 0; r < 16; ++r) acc[a][r] = 0.f;
      short8 U[32], V[32];
      const u16* h1p = h1h + (size_t)t * 65536 + (size_t)w * 32768
                       + (size_t)hi * 256 + (size_t)b * 8;
      const u16* h0p = h0h + (size_t)(t + 1) * 65536 + (size_t)w * 32768
                       + (size_t)hi * 256 + (size_t)b * 8;
      if (t > 0) {
        poll(f1w, (u32)t);
        #pragma unroll
        for (int j = 0; j < 32; ++j) U[j] = *(const short8*)(h1p + j * 512);
      }
      poll(f0w, (u32)(t + 1));            // overlaps U flight
      #pragma unroll
      for (int j = 0; j < 32; ++j) V[j] = *(const short8*)(h0p + j * 512);
      if (t > 0) {
        #pragma unroll
        for (int j = 0; j < 32; ++j) MFMA_T(U[j], 64 + j);
        #pragma unroll
        for (int j = 0; j < 32; ++j) U[j] = *(const short8*)(h1p + 16384 + j * 512);
      }
      #pragma unroll
      for (int j = 0; j < 32; ++j) MFMA_T(V[j], j);
      #pragma unroll
      for (int j = 0; j < 32; ++j) V[j] = *(const short8*)(h0p + 16384 + j * 512);
      if (t > 0) {
        #pragma unroll
        for (int j = 0; j < 32; ++j) MFMA_T(U[j], 96 + j);
      }
      #pragma unroll
      for (int j = 0; j < 32; ++j) MFMA_T(V[j], 32 + j);
      publish(t, h1h);
    }
  }
  #undef MFMA_T

  // ---- FC + softmax epilogue: block 0, wave 0 (reads h1[511] = slot 512) ----
  if (cu == 0 && tid < 64) {
    #pragma unroll
    for (int j = 0; j < 4; ++j) {        // all 256 layer-1 flags >= 512
      const u32* p = flags + (size_t)(256 + lane + 64 * j) * 8;
      for (;;) {
        u32 v;
        asm volatile("global_load_dword %0, %1, off sc0 sc1\n\ts_waitcnt vmcnt(0)"
                     : "=v"(v) : "v"(p) : "memory");
        if (v >= 512u) break;
        __builtin_amdgcn_s_sleep(1);
      }
    }
    const int bb = lane;                 // one batch per lane
    const u16* hb = h1h + (size_t)512 * 65536 + (size_t)(bb >> 5) * 32768
                    + (size_t)(bb & 31) * 8;
    float s0 = fc_b[0], s1 = fc_b[1];
    for (int c = 0; c < 128; ++c) {
      short8 hv8 = *(const short8*)(hb + (size_t)c * 256);
      #pragma unroll
      for (int e = 0; e < 8; ++e) {
        float hv = bf2f((u16)hv8[e]);
        s0 += hv * fc_w[c * 8 + e];
        s1 += hv * fc_w[1024 + c * 8 + e];
      }
    }
    float mx = fmaxf(s0, s1);
    float e0 = __expf(s0 - mx), e1 = __expf(s1 - mx);
    float inv = 1.0f / (e0 + e1);
    out[bb * 2]     = e0 * inv;
    out[bb * 2 + 1] = e1 * inv;
  }
}

extern "C" void kernel_launch(void* const* d_in, const int* in_sizes, int n_in,
                              void* d_out, int out_size, void* d_ws, size_t ws_size,
                              hipStream_t stream) {
  const float* x    = (const float*)d_in[0];
  const float* wih0 = (const float*)d_in[1];
  const float* whh0 = (const float*)d_in[2];
  const float* bih0 = (const float*)d_in[3];
  const float* bhh0 = (const float*)d_in[4];
  const float* wih1 = (const float*)d_in[5];
  const float* whh1 = (const float*)d_in[6];
  const float* bih1 = (const float*)d_in[7];
  const float* bhh1 = (const float*)d_in[8];
  const float* fcw  = (const float*)d_in[9];
  const float* fcb  = (const float*)d_in[10];
  float* out = (float*)d_out;
  char* ws = (char*)d_ws;

  u16* xb    = (u16*)(ws + XB_OFF);
  u16* h0h   = (u16*)(ws + H0_OFF);
  u16* h1h   = (u16*)(ws + H1_OFF);
  u32* flags = (u32*)(ws + FL_OFF);

  (void)hipFuncSetAttribute((const void*)lstm_persist,
      hipFuncAttributeMaxDynamicSharedMemorySize, LDS_TOTAL);

  hipMemsetAsync(ws + FL_OFF, 0, FLAGS_LEN, stream);   // zero step flags
  prep_x<<<8192, 256, 0, stream>>>(x, xb);
  lstm_persist<<<256, 128, LDS_TOTAL, stream>>>(
      (const u16*)xb, wih0, whh0, bih0, bhh0, wih1, whh1, bih1, bhh1,
      h0h, h1h, flags, fcw, fcb, out);
}